// Round 9
// baseline (680.231 us; speedup 1.0000x reference)
//
#include <hip/hip_runtime.h>
#include <hip/hip_bf16.h>
#include <float.h>

// Problem constants: B=4, S=2048, D=1024, C=16384, k=8
#define R_TOTAL 8192
#define D_DIM   1024
#define C_TOTAL 16384
#define KSEL    8
#define XN  ((size_t)R_TOTAL * D_DIM)
#define NSPLIT  8
#define SEGC    (C_TOTAL / NSPLIT)      // 2048 codes per segment
#define NCHUNK  16                      // chunks of 128 codes per segment
#define NKT     (NCHUNK * 16)           // 256 K-tiles (BK=64 bytes) per block
#define KEEP    12                      // per-segment keep depth (i8 noise margin)
#define NC_RES  28                      // candidates exact-rescored per row

typedef __attribute__((ext_vector_type(4)))  int  int4v;    // 16B i8 frag
typedef __attribute__((ext_vector_type(16))) int  i32x16;   // acc
typedef __attribute__((ext_vector_type(4)))  float f32x4;

__device__ __forceinline__ void gload_lds16(const void* g, void* l) {
  __builtin_amdgcn_global_load_lds((const __attribute__((address_space(1))) void*)g,
                                   (__attribute__((address_space(3))) void*)l, 16, 0, 0);
}

// ---------------------------------------------------------------------------
// Kernel 0: per-row absmax quantize f32 -> i8 (X and CB), plus CB sumsq (c2)
// and scales. One wave per row.
// ---------------------------------------------------------------------------
__global__ __launch_bounds__(256)
void quant_kernel(const float* __restrict__ X, const float* __restrict__ CB,
                  signed char* __restrict__ Xq, signed char* __restrict__ CBq,
                  float* __restrict__ sxg, float* __restrict__ scg,
                  float* __restrict__ c2g) {
  const int row  = blockIdx.x * 4 + (threadIdx.x >> 6);
  const int lane = threadIdx.x & 63;
  const bool isCB = row >= R_TOTAL;
  const int rl = isCB ? row - R_TOTAL : row;
  const float* src = (isCB ? CB : X) + (size_t)rl * D_DIM;
  signed char* dst = (isCB ? CBq : Xq) + (size_t)rl * D_DIM;

  float4 v[4];
  float amax = 0.f, ss = 0.f;
  #pragma unroll
  for (int i = 0; i < 4; ++i) {
    v[i] = *(const float4*)(src + i * 256 + lane * 4);
    amax = fmaxf(amax, fmaxf(fmaxf(fabsf(v[i].x), fabsf(v[i].y)),
                             fmaxf(fabsf(v[i].z), fabsf(v[i].w))));
    ss += v[i].x * v[i].x + v[i].y * v[i].y + v[i].z * v[i].z + v[i].w * v[i].w;
  }
  #pragma unroll
  for (int off = 32; off >= 1; off >>= 1) {
    amax = fmaxf(amax, __shfl_xor(amax, off, 64));
    ss += __shfl_xor(ss, off, 64);
  }
  const float qs = (amax > 0.f) ? 127.f / amax : 0.f;
  #pragma unroll
  for (int i = 0; i < 4; ++i) {
    int q0 = (int)rintf(fminf(fmaxf(v[i].x * qs, -127.f), 127.f));
    int q1 = (int)rintf(fminf(fmaxf(v[i].y * qs, -127.f), 127.f));
    int q2 = (int)rintf(fminf(fmaxf(v[i].z * qs, -127.f), 127.f));
    int q3 = (int)rintf(fminf(fmaxf(v[i].w * qs, -127.f), 127.f));
    const int packed = (q0 & 255) | ((q1 & 255) << 8) | ((q2 & 255) << 16) | (q3 << 24);
    ((int*)dst)[i * 64 + lane] = packed;
  }
  if (lane == 0) {
    const float s = (amax > 0.f) ? amax / 127.f : 0.f;
    if (isCB) { scg[rl] = s; c2g[rl] = ss; }
    else      { sxg[rl] = s; }
  }
}

// ---------------------------------------------------------------------------
// Kernel 1: i8 MFMA GEMM (S^T: 128 codes x 128 xrows tile) + fused per-xrow
// approximate top-12 per 2048-code segment.
// 256 thr = 4 waves (wr=code half, wc=xrow half); per wave 64x64 out via
// mfma_i32_32x32x32_i8: acc[fm=2][fn=2] i32x16. BK = 64 bytes (K elems).
// LDS 50176B dyn: As dbuf 2x8KB @0 | Xs dbuf 2x8KB @16KB | c2s @32KB |
//                 scs @40KB (merge phase reuses base: mv/mi 2x25088B).
// ~170 regs, 50KB -> 2 blocks/CU: inter-block TLP covers barrier stalls
// (m97 mechanism) instead of intra-block pipelining.
// Sync per tile: STAGE_A(g+1); vmcnt(2); barrier; {slice0 reads+4 MFMA;
// slice1 reads + STAGE_X(g+1) + 4 MFMA}; [chunk epilogue]; barrier.
// Swizzle: rows [*][64B], col16 ^= ((row&3)<<4) on global src + reads
// (both sides, #21). NOTE: LDS buffer pointers computed inline (pointer
// ARRAYS of LDS addrs are a hipcc static-initializer bug - r8 compile fail).
// ---------------------------------------------------------------------------
__global__ __launch_bounds__(256, 2)
void gemm_topk_kernel(const signed char* __restrict__ Xq,
                      const signed char* __restrict__ CBq,
                      const float* __restrict__ c2g, const float* __restrict__ scg,
                      const float* __restrict__ sxg,
                      float* __restrict__ pval, int* __restrict__ pid) {
  extern __shared__ char smem[];
  float* c2s = (float*)(smem + 32768);
  float* scs = (float*)(smem + 40960);

  const int t   = threadIdx.x;
  const int wid = t >> 6, l = t & 63;
  const int wr  = wid >> 1;           // code half (64 rows)
  const int wc  = wid & 1;            // xrow half (64 cols)
  const int l31 = l & 31, hi = l >> 5;

  // XCD chunk swizzle: grid 512, 8 XCDs -> each XCD owns one segment (2MB L2-fit)
  const int bid  = (int)((blockIdx.x & 7) * 64 + (blockIdx.x >> 3));
  const int xt   = bid & 63;
  const int seg  = bid >> 6;
  const int xbase = xt * 128;
  const int cb0   = seg * SEGC;

  // preload segment c2 + sc into LDS
  #pragma unroll
  for (int j = 0; j < 2; ++j) {
    const int idx = (j * 256 + t) * 4;
    *(float4*)&c2s[idx] = *(const float4*)(c2g + cb0 + idx);
    *(float4*)&scs[idx] = *(const float4*)(scg + cb0 + idx);
  }
  // per-lane xrow scales (anchor as live so loads stay before the loop)
  float fx2[2];
  #pragma unroll
  for (int fn = 0; fn < 2; ++fn)
    fx2[fn] = 2.f * sxg[xbase + wc * 64 + fn * 32 + l31];
  asm volatile("" :: "v"(fx2[0]), "v"(fx2[1]));

  // staging map: issue i covers rows i*64 + (t>>2); 16B col (t&3), swizzled src
  const int srow = t >> 2;
  const int scol = ((t & 3) * 16) ^ ((srow & 3) << 4);

  i32x16 acc[2][2];
  float tv[2][KEEP]; int ti[2][KEEP];
  #pragma unroll
  for (int fm = 0; fm < 2; ++fm)
    #pragma unroll
    for (int fn = 0; fn < 2; ++fn)
      #pragma unroll
      for (int r = 0; r < 16; ++r) acc[fm][fn][r] = 0;
  #pragma unroll
  for (int fn = 0; fn < 2; ++fn)
    #pragma unroll
    for (int q = 0; q < KEEP; ++q) { tv[fn][q] = -FLT_MAX; ti[fn][q] = 0; }

  auto STAGE_A = [&](int g) {   // 2 x gload16: 128 rows x 64B of K-tile g
    const int kbase = (g & 15) * 64;
    const int arow0 = cb0 + (g >> 4) * 128;
    char* dst = smem + (g & 1) * 8192;
    #pragma unroll
    for (int i = 0; i < 2; ++i)
      gload_lds16(CBq + (size_t)(arow0 + i * 64 + srow) * D_DIM + kbase + scol,
                  dst + i * 4096 + t * 16);
  };
  auto STAGE_X = [&](int g) {
    const int kbase = (g & 15) * 64;
    char* dst = smem + 16384 + (g & 1) * 8192;
    #pragma unroll
    for (int i = 0; i < 2; ++i)
      gload_lds16(Xq + (size_t)(xbase + i * 64 + srow) * D_DIM + kbase + scol,
                  dst + i * 4096 + t * 16);
  };

  STAGE_A(0); STAGE_X(0);

  const int rsw = (l31 & 3) << 4;   // read-side swizzle (row&3 == l31&3)

  for (int g = 0; g < NKT; ++g) {
    const char* Ab = smem + (g & 1) * 8192;
    const char* Xb = smem + 16384 + (g & 1) * 8192;
    const bool more = (g + 1 < NKT);

    if (more) {
      STAGE_A(g + 1);                                   // 2 vm ops, other buffer
      asm volatile("s_waitcnt vmcnt(2)" ::: "memory");  // A(g),X(g) landed
    } else {
      asm volatile("s_waitcnt vmcnt(0)" ::: "memory");
    }
    __builtin_amdgcn_s_barrier();

    #pragma unroll
    for (int p = 0; p < 2; ++p) {     // two K=32 slices per 64B tile
      const int kb = (p * 32 + hi * 16) ^ rsw;
      int4v a0 = *(const int4v*)(Ab + (wr * 64 +      l31) * 64 + kb);
      int4v a1 = *(const int4v*)(Ab + (wr * 64 + 32 + l31) * 64 + kb);
      int4v b0 = *(const int4v*)(Xb + (wc * 64 +      l31) * 64 + kb);
      int4v b1 = *(const int4v*)(Xb + (wc * 64 + 32 + l31) * 64 + kb);
      if (p == 1 && more) STAGE_X(g + 1);
      __builtin_amdgcn_s_setprio(1);
      acc[0][0] = __builtin_amdgcn_mfma_i32_32x32x32_i8(a0, b0, acc[0][0], 0, 0, 0);
      acc[0][1] = __builtin_amdgcn_mfma_i32_32x32x32_i8(a0, b1, acc[0][1], 0, 0, 0);
      acc[1][0] = __builtin_amdgcn_mfma_i32_32x32x32_i8(a1, b0, acc[1][0], 0, 0, 0);
      acc[1][1] = __builtin_amdgcn_mfma_i32_32x32x32_i8(a1, b1, acc[1][1], 0, 0, 0);
      __builtin_amdgcn_s_setprio(0);
    }

    if ((g & 15) == 15) {
      // ---- selection epilogue for chunk ch (128 codes), registers + LDS ----
      const int ch = g >> 4;
      #pragma unroll
      for (int fm = 0; fm < 2; ++fm) {
        #pragma unroll
        for (int q = 0; q < 4; ++q) {
          const int rloc = ch * 128 + wr * 64 + fm * 32 + q * 8 + hi * 4;
          const f32x4 cq = *(const f32x4*)&c2s[rloc];
          const f32x4 sq = *(const f32x4*)&scs[rloc];
          #pragma unroll
          for (int fn = 0; fn < 2; ++fn) {
            #pragma unroll
            for (int r = 0; r < 4; ++r) {
              const float d = (float)acc[fm][fn][q * 4 + r];   // |dot|<2^24: exact
              const float s = fx2[fn] * sq[r] * d - cq[r];
              if (s > tv[fn][KEEP - 1]) {     // strict >: ids scanned ascending
                float cv = s; int ci = cb0 + rloc + r;
                #pragma unroll
                for (int q2 = 0; q2 < KEEP; ++q2) {
                  if (cv > tv[fn][q2]) {
                    const float t0 = tv[fn][q2]; tv[fn][q2] = cv; cv = t0;
                    const int   t1 = ti[fn][q2]; ti[fn][q2] = ci; ci = t1;
                  }
                }
              }
            }
          }
        }
      }
      #pragma unroll
      for (int fm = 0; fm < 2; ++fm)
        #pragma unroll
        for (int fn = 0; fn < 2; ++fn)
          #pragma unroll
          for (int r = 0; r < 16; ++r) acc[fm][fn][r] = 0;
    }

    __builtin_amdgcn_s_barrier();   // reads of buf g&1 done before g+2 stage
  }

  // ---- merge 4 lane-lists per xrow (wr x hi), write per-segment top-12 ----
  asm volatile("s_waitcnt vmcnt(0) lgkmcnt(0)" ::: "memory");
  __builtin_amdgcn_s_barrier();
  float* mv = (float*)smem;               // [128][49] f32 (4 lists x 12, +1 pad)
  int*   mi = (int*)(smem + 25088);
  #pragma unroll
  for (int fn = 0; fn < 2; ++fn) {
    const int xrL = wc * 64 + fn * 32 + l31;
    const int li  = wr * 2 + hi;
    #pragma unroll
    for (int q = 0; q < KEEP; ++q) {
      mv[xrL * 49 + li * KEEP + q] = tv[fn][q];
      mi[xrL * 49 + li * KEEP + q] = ti[fn][q];
    }
  }
  __syncthreads();
  if (t < 128) {
    float bvv[KEEP]; int bii[KEEP];
    #pragma unroll
    for (int q = 0; q < KEEP; ++q) { bvv[q] = -FLT_MAX; bii[q] = 0x7fffffff; }
    for (int c = 0; c < 4 * KEEP; ++c) {
      float cv = mv[t * 49 + c]; int ci = mi[t * 49 + c];
      if (cv > bvv[KEEP - 1] || (cv == bvv[KEEP - 1] && ci < bii[KEEP - 1])) {
        #pragma unroll
        for (int q = 0; q < KEEP; ++q) {
          if (cv > bvv[q] || (cv == bvv[q] && ci < bii[q])) {
            const float t0 = bvv[q]; bvv[q] = cv; cv = t0;
            const int   t1 = bii[q]; bii[q] = ci; ci = t1;
          }
        }
      }
    }
    const size_t base = ((size_t)(xbase + t) * NSPLIT + seg) * KEEP;
    #pragma unroll
    for (int q = 0; q < KEEP; ++q) { pval[base + q] = bvv[q]; pid[base + q] = bii[q]; }
  }
}

// ---------------------------------------------------------------------------
// Kernel 2: per row: merge 96 approx candidates -> top-28, exact f32 rescore,
// final top-8 (ties: lower id), gather + average.
// ---------------------------------------------------------------------------
__global__ __launch_bounds__(256)
void rescore_kernel(const float* __restrict__ X, const float* __restrict__ CB,
                    const float* __restrict__ c2g,
                    const float* __restrict__ pval, const int* __restrict__ pid,
                    float* __restrict__ out, float* __restrict__ out_ids) {
  const int row = blockIdx.x;
  const int t = threadIdx.x;
  __shared__ float xs[D_DIM];
  __shared__ int   scid[NC_RES];
  __shared__ float sv[NC_RES];
  __shared__ int   topid[KSEL];

  *(float4*)&xs[t * 4] = *(const float4*)(X + (size_t)row * D_DIM + t * 4);

  const int ncand = NSPLIT * KEEP;   // 96

  if (t < 64) {   // wave 0: lane holds cand t and (t<32 ? t+64 : none)
    float v0 = pval[(size_t)row * ncand + t];
    int   i0 = pid [(size_t)row * ncand + t];
    float v1 = -FLT_MAX; int i1 = 0x7fffffff;
    if (t < 32) {
      v1 = pval[(size_t)row * ncand + t + 64];
      i1 = pid [(size_t)row * ncand + t + 64];
    }
    for (int it = 0; it < NC_RES; ++it) {
      float bv; int bid;
      if (v0 > v1 || (v0 == v1 && i0 < i1)) { bv = v0; bid = i0; }
      else                                  { bv = v1; bid = i1; }
      #pragma unroll
      for (int off = 32; off >= 1; off >>= 1) {
        float ov = __shfl_xor(bv, off, 64);
        int   oi = __shfl_xor(bid, off, 64);
        if (ov > bv || (ov == bv && oi < bid)) { bv = ov; bid = oi; }
      }
      if (t == 0) scid[it] = bid;
      if (i0 == bid) v0 = -FLT_MAX;
      if (i1 == bid) v1 = -FLT_MAX;
    }
  }
  __syncthreads();

  const int w = t >> 6, ln = t & 63;
  for (int c = w; c < NC_RES; c += 4) {
    const int id = scid[c];
    const float* cr = CB + (size_t)id * D_DIM;
    float s = 0.f;
    #pragma unroll
    for (int i = 0; i < 4; ++i) {
      const float4 cv = *(const float4*)(cr + ln * 4 + i * 256);
      const float4 xv = *(const float4*)&xs[ln * 4 + i * 256];
      s += cv.x * xv.x + cv.y * xv.y + cv.z * xv.z + cv.w * xv.w;
    }
    #pragma unroll
    for (int off = 32; off >= 1; off >>= 1) s += __shfl_xor(s, off, 64);
    if (ln == 0) sv[c] = 2.f * s - c2g[id];
  }
  __syncthreads();

  if (t == 0) {
    float bv[KSEL]; int bi[KSEL];
    #pragma unroll
    for (int q = 0; q < KSEL; ++q) { bv[q] = -FLT_MAX; bi[q] = 0x7fffffff; }
    for (int c = 0; c < NC_RES; ++c) {
      float cv = sv[c]; int ci = scid[c];
      #pragma unroll
      for (int q = 0; q < KSEL; ++q) {
        if (cv > bv[q] || (cv == bv[q] && ci < bi[q])) {
          const float t0 = bv[q]; bv[q] = cv; cv = t0;
          const int   t1 = bi[q]; bi[q] = ci; ci = t1;
        }
      }
    }
    #pragma unroll
    for (int q = 0; q < KSEL; ++q) {
      topid[q] = bi[q];
      out_ids[(size_t)row * KSEL + q] = (float)bi[q];
    }
  }
  __syncthreads();

  float4 a = {0.f, 0.f, 0.f, 0.f};
  #pragma unroll
  for (int q = 0; q < KSEL; ++q) {
    const float4 cv = *(const float4*)(CB + (size_t)topid[q] * D_DIM + t * 4);
    a.x += cv.x; a.y += cv.y; a.z += cv.z; a.w += cv.w;
  }
  a.x *= 0.125f; a.y *= 0.125f; a.z *= 0.125f; a.w *= 0.125f;
  *(float4*)(out + (size_t)row * D_DIM + t * 4) = a;
}

// ---------------------------------------------------------------------------
extern "C" void kernel_launch(void* const* d_in, const int* in_sizes, int n_in,
                              void* d_out, int out_size, void* d_ws, size_t ws_size,
                              hipStream_t stream) {
  const float* X  = (const float*)d_in[0];
  const float* CB = (const float*)d_in[1];
  // d_in[2] = kcodes, fixed at 8 (compiled in)

  float* out     = (float*)d_out;
  float* out_ids = out + XN;

  const size_t XqB  = XN;                        // 8 MB (i8)
  const size_t CBqB = (size_t)C_TOTAL * D_DIM;   // 16 MB (i8)
  const size_t sxB  = R_TOTAL * 4;               // 32 KB
  const size_t scB  = C_TOTAL * 4;               // 64 KB
  const size_t c2B  = C_TOTAL * 4;               // 64 KB
  const size_t pvB  = (size_t)R_TOTAL * NSPLIT * KEEP * 4;  // 3 MB

  char* p = (char*)d_ws;
  signed char* CBq;
  if (ws_size >= XqB + CBqB + sxB + scB + c2B + 2 * pvB) {
    CBq = (signed char*)p; p += CBqB;
  } else {
    // CBq lives in d_out's outputs region (16MB of 32MB; overwritten at end)
    CBq = (signed char*)d_out;
  }
  signed char* Xq = (signed char*)p; p += XqB;
  float* sxg  = (float*)p; p += sxB;
  float* scg  = (float*)p; p += scB;
  float* c2g  = (float*)p; p += c2B;
  float* pval = (float*)p; p += pvB;
  int*   pid  = (int*)p;

  hipLaunchKernelGGL(quant_kernel, dim3((R_TOTAL + C_TOTAL) / 4), dim3(256), 0, stream,
                     X, CB, Xq, CBq, sxg, scg, c2g);
  hipLaunchKernelGGL(gemm_topk_kernel, dim3(64 * NSPLIT), dim3(256), 50176, stream,
                     Xq, CBq, c2g, scg, sxg, pval, pid);
  hipLaunchKernelGGL(rescore_kernel, dim3(R_TOTAL), dim3(256), 0, stream,
                     X, CB, c2g, pval, pid, out, out_ids);
}

// Round 10
// 671.870 us; speedup vs baseline: 1.0124x; 1.0124x over previous
//
#include <hip/hip_runtime.h>
#include <hip/hip_bf16.h>
#include <float.h>

// Problem constants: B=4, S=2048, D=1024, C=16384, k=8
#define R_TOTAL 8192
#define D_DIM   1024
#define C_TOTAL 16384
#define KSEL    8
#define XN  ((size_t)R_TOTAL * D_DIM)
#define NSPLIT  8
#define SEGC    (C_TOTAL / NSPLIT)      // 2048 codes per segment (per block)
#define NKT     64                      // K-tiles: 8 chunks x 8 (BK=128 i8 elems)
#define KEEP    12                      // per-segment keep depth (i8 noise margin)
#define NC_RES  28                      // candidates exact-rescored per row

typedef __attribute__((ext_vector_type(4)))  int  int4v;    // 16B i8 frag
typedef __attribute__((ext_vector_type(16))) int  i32x16;   // acc
typedef __attribute__((ext_vector_type(4)))  float f32x4;

__device__ __forceinline__ void gload_lds16(const void* g, void* l) {
  __builtin_amdgcn_global_load_lds((const __attribute__((address_space(1))) void*)g,
                                   (__attribute__((address_space(3))) void*)l, 16, 0, 0);
}

// ---------------------------------------------------------------------------
// Kernel 0: per-row absmax quantize f32 -> i8 (X and CB) + CB sumsq + scales.
// One wave per row. (unchanged from r9, passed)
// ---------------------------------------------------------------------------
__global__ __launch_bounds__(256)
void quant_kernel(const float* __restrict__ X, const float* __restrict__ CB,
                  signed char* __restrict__ Xq, signed char* __restrict__ CBq,
                  float* __restrict__ sxg, float* __restrict__ scg,
                  float* __restrict__ c2g) {
  const int row  = blockIdx.x * 4 + (threadIdx.x >> 6);
  const int lane = threadIdx.x & 63;
  const bool isCB = row >= R_TOTAL;
  const int rl = isCB ? row - R_TOTAL : row;
  const float* src = (isCB ? CB : X) + (size_t)rl * D_DIM;
  signed char* dst = (isCB ? CBq : Xq) + (size_t)rl * D_DIM;

  float4 v[4];
  float amax = 0.f, ss = 0.f;
  #pragma unroll
  for (int i = 0; i < 4; ++i) {
    v[i] = *(const float4*)(src + i * 256 + lane * 4);
    amax = fmaxf(amax, fmaxf(fmaxf(fabsf(v[i].x), fabsf(v[i].y)),
                             fmaxf(fabsf(v[i].z), fabsf(v[i].w))));
    ss += v[i].x * v[i].x + v[i].y * v[i].y + v[i].z * v[i].z + v[i].w * v[i].w;
  }
  #pragma unroll
  for (int off = 32; off >= 1; off >>= 1) {
    amax = fmaxf(amax, __shfl_xor(amax, off, 64));
    ss += __shfl_xor(ss, off, 64);
  }
  const float qs = (amax > 0.f) ? 127.f / amax : 0.f;
  #pragma unroll
  for (int i = 0; i < 4; ++i) {
    int q0 = (int)rintf(fminf(fmaxf(v[i].x * qs, -127.f), 127.f));
    int q1 = (int)rintf(fminf(fmaxf(v[i].y * qs, -127.f), 127.f));
    int q2 = (int)rintf(fminf(fmaxf(v[i].z * qs, -127.f), 127.f));
    int q3 = (int)rintf(fminf(fmaxf(v[i].w * qs, -127.f), 127.f));
    const int packed = (q0 & 255) | ((q1 & 255) << 8) | ((q2 & 255) << 16) | (q3 << 24);
    ((int*)dst)[i * 64 + lane] = packed;
  }
  if (lane == 0) {
    const float s = (amax > 0.f) ? amax / 127.f : 0.f;
    if (isCB) { scg[rl] = s; c2g[rl] = ss; }
    else      { sxg[rl] = s; }
  }
}

// ---------------------------------------------------------------------------
// Kernel 1: i8 MFMA GEMM (S^T: 256 codes x 256 xrows tile) + fused per-xrow
// approximate top-12 per 2048-code segment.
// EXACT r6 structure (best measured, 418us at bf16) with i8 payload:
// rows are 128 BYTES either way -> identical staging (8x gload16/thread),
// identical swizzle, identical b128 fragment reads, 32 MFMA/tile/wave via
// mfma_i32_32x32x32_i8 (K=32/instr) -> each K-tile covers 128 K-elems,
// NKT 128 -> 64 at constant per-tile cost.
// 512 thr = 8 waves (wr= code half 128, wc = xrow quarter 64).
// LDS 144KB: A dbuf 2x32KB @0 | X dbuf 2x32KB @64KB | c2s @128KB | scs @136KB.
// E/O one-phase-ahead register pipeline, 4 barriers/tile (r6 verbatim).
// Swizzle: row byte ^= ((row&7)<<4) on global src + read addrs (#21).
// ---------------------------------------------------------------------------
__global__ __launch_bounds__(512, 2)
void gemm_topk_kernel(const signed char* __restrict__ Xq,
                      const signed char* __restrict__ CBq,
                      const float* __restrict__ c2g, const float* __restrict__ scg,
                      const float* __restrict__ sxg,
                      float* __restrict__ pval, int* __restrict__ pid) {
  extern __shared__ char smem[];
  float* c2s = (float*)(smem + 131072);
  float* scs = (float*)(smem + 139264);

  const int t   = threadIdx.x;
  const int wid = t >> 6, l = t & 63;
  const int wr  = wid >> 2;          // 0..1: code half (128 rows)
  const int wc  = wid & 3;           // 0..3: xrow quarter (64 cols)
  const int l31 = l & 31, hi = l >> 5;

  const int xt    = blockIdx.x & 31;        // 32 xrow tiles (r6 mapping, no swizzle)
  const int seg   = blockIdx.x >> 5;        // 8 segments
  const int xbase = xt * 256;
  const int cb0   = seg * SEGC;

  // preload segment c2 + sc into LDS (512 thr x float4 = 2048 f32 each)
  *(float4*)&c2s[t * 4] = *(const float4*)(c2g + cb0 + t * 4);
  *(float4*)&scs[t * 4] = *(const float4*)(scg + cb0 + t * 4);

  // per-lane xrow scales (2*sx), one per fn block
  float fx2[2];
  #pragma unroll
  for (int fn = 0; fn < 2; ++fn)
    fx2[fn] = 2.f * sxg[xbase + wc * 64 + fn * 32 + l31];
  asm volatile("" :: "v"(fx2[0]), "v"(fx2[1]));

  // staging: issue i covers rows i*64+(t>>3); 16B col (t&7), swizzled src (bytes)
  const int srow = t >> 3;
  const int sswz = ((t & 7) * 16) ^ ((srow & 7) << 4);   // byte offset in 128B row
  const int fswz = (l & 7) << 4;                          // read swizzle

  i32x16 acc[4][2];
  float tv[2][KEEP]; int ti[2][KEEP];
  #pragma unroll
  for (int fm = 0; fm < 4; ++fm)
    #pragma unroll
    for (int fn = 0; fn < 2; ++fn)
      #pragma unroll
      for (int r = 0; r < 16; ++r) acc[fm][fn][r] = 0;
  #pragma unroll
  for (int fn = 0; fn < 2; ++fn)
    #pragma unroll
    for (int q = 0; q < KEEP; ++q) { tv[fn][q] = -FLT_MAX; ti[fn][q] = 0; }

  auto STAGE_A = [&](int g) {   // 4 x gload16: 256 code rows x 128B of K-tile g
    const int kbase = (g & 7) * 128;
    const int arow0 = cb0 + (g >> 3) * 256;
    char* As = smem + (g & 1) * 32768;
    #pragma unroll
    for (int i = 0; i < 4; ++i)
      gload_lds16(CBq + (size_t)(arow0 + i * 64 + srow) * D_DIM + kbase + sswz,
                  As + (i * 512 + t) * 16);
  };
  auto STAGE_X = [&](int g) {
    const int kbase = (g & 7) * 128;
    char* Xs = smem + 65536 + (g & 1) * 32768;
    #pragma unroll
    for (int i = 0; i < 4; ++i)
      gload_lds16(Xq + (size_t)(xbase + i * 64 + srow) * D_DIM + kbase + sswz,
                  Xs + (i * 512 + t) * 16);
  };

  // two named fragment sets (static indexing only - rule 20)
  int4v avE[4], bvE[2], avO[4], bvO[2];

#define READ_FRAGS(AV, BV, ABUF, XBUF, P)                                       \
  {                                                                             \
    const int kb_ = ((P) * 32 + hi * 16) ^ fswz;                                \
    _Pragma("unroll")                                                           \
    for (int fm_ = 0; fm_ < 4; ++fm_)                                           \
      AV[fm_] = *(const int4v*)((ABUF) +                                        \
                    (wr * 128 + fm_ * 32 + l31) * 128 + kb_);                   \
    _Pragma("unroll")                                                           \
    for (int fn_ = 0; fn_ < 2; ++fn_)                                           \
      BV[fn_] = *(const int4v*)((XBUF) +                                        \
                    (wc * 64 + fn_ * 32 + l31) * 128 + kb_);                    \
  }

#define MFMA8(AV, BV)                                                           \
  {                                                                             \
    __builtin_amdgcn_s_setprio(1);                                              \
    _Pragma("unroll")                                                           \
    for (int fm_ = 0; fm_ < 4; ++fm_)                                           \
      _Pragma("unroll")                                                         \
      for (int fn_ = 0; fn_ < 2; ++fn_)                                         \
        acc[fm_][fn_] = __builtin_amdgcn_mfma_i32_32x32x32_i8(                  \
            AV[fm_], BV[fn_], acc[fm_][fn_], 0, 0, 0);                          \
    __builtin_amdgcn_s_setprio(0);                                              \
    __builtin_amdgcn_sched_barrier(0);                                          \
  }

  // ---- prologue: stage tile 0, drain, pre-read ks0 frags ----
  STAGE_A(0); STAGE_X(0);
  asm volatile("s_waitcnt vmcnt(0) lgkmcnt(0)" ::: "memory");  // buf0 + c2s/scs
  __builtin_amdgcn_s_barrier();
  __builtin_amdgcn_sched_barrier(0);
  READ_FRAGS(avE, bvE, (const char*)smem, (const char*)smem + 65536, 0);

  for (int g = 0; g < NKT; ++g) {
    const char* As  = smem + (g & 1) * 32768;
    const char* Xs  = smem + 65536 + (g & 1) * 32768;
    const char* Asn = smem + ((g + 1) & 1) * 32768;
    const char* Xsn = smem + 65536 + ((g + 1) & 1) * 32768;
    const bool more = (g + 1 < NKT);

    // --- p0: consume E(ks0), issue O(ks1), stage A(g+1) ---
    READ_FRAGS(avO, bvO, As, Xs, 1);
    if (more) STAGE_A(g + 1);
    __builtin_amdgcn_s_barrier();
    MFMA8(avE, bvE);

    // --- p1: consume O(ks1), issue E(ks2), stage X(g+1) ---
    READ_FRAGS(avE, bvE, As, Xs, 2);
    if (more) STAGE_X(g + 1);
    __builtin_amdgcn_s_barrier();
    MFMA8(avO, bvO);

    // --- p2: consume E(ks2), issue O(ks3) ---
    READ_FRAGS(avO, bvO, As, Xs, 3);
    __builtin_amdgcn_s_barrier();
    MFMA8(avE, bvE);

    // --- p3: consume O(ks3), pre-read E(ks0 of g+1) from other buffer ---
    asm volatile("s_waitcnt vmcnt(0)" ::: "memory");  // stage g+1: 2-3 phases old
    __builtin_amdgcn_s_barrier();                      // ALL waves' stages landed
    __builtin_amdgcn_sched_barrier(0);
    if (more) READ_FRAGS(avE, bvE, Asn, Xsn, 0);
    MFMA8(avO, bvO);

    if ((g & 7) == 7) {
      // ---- selection epilogue for chunk ch (256 codes): dequant + top-12 ----
      const int ch = g >> 3;
      #pragma unroll
      for (int fm = 0; fm < 4; ++fm) {
        #pragma unroll
        for (int q = 0; q < 4; ++q) {
          const int rloc = ch * 256 + wr * 128 + fm * 32 + q * 8 + hi * 4;
          const f32x4 cq = *(const f32x4*)&c2s[rloc];
          const f32x4 sq = *(const f32x4*)&scs[rloc];
          #pragma unroll
          for (int fn = 0; fn < 2; ++fn) {
            #pragma unroll
            for (int r = 0; r < 4; ++r) {
              const float d = (float)acc[fm][fn][q * 4 + r];   // |dot|<2^24: exact
              const float s = fx2[fn] * sq[r] * d - cq[r];
              if (s > tv[fn][KEEP - 1]) {     // strict >: ids scanned ascending
                float cv = s; int ci = cb0 + rloc + r;
                #pragma unroll
                for (int q2 = 0; q2 < KEEP; ++q2) {
                  if (cv > tv[fn][q2]) {
                    const float t0 = tv[fn][q2]; tv[fn][q2] = cv; cv = t0;
                    const int   t1 = ti[fn][q2]; ti[fn][q2] = ci; ci = t1;
                  }
                }
              }
            }
          }
        }
      }
      #pragma unroll
      for (int fm = 0; fm < 4; ++fm)
        #pragma unroll
        for (int fn = 0; fn < 2; ++fn)
          #pragma unroll
          for (int r = 0; r < 16; ++r) acc[fm][fn][r] = 0;
    }
  }

#undef READ_FRAGS
#undef MFMA8

  // ---- merge 4 lane-lists per xrow (wr x hi), write per-segment top-12 ----
  asm volatile("s_waitcnt vmcnt(0) lgkmcnt(0)" ::: "memory");
  __builtin_amdgcn_s_barrier();
  float* mv = (float*)smem;               // [256 xrows][49] f32 (4x12, +1 pad)
  int*   mi = (int*)(smem + 51200);
  #pragma unroll
  for (int fn = 0; fn < 2; ++fn) {
    const int xrL = wc * 64 + fn * 32 + l31;
    const int li  = wr * 2 + hi;
    #pragma unroll
    for (int q = 0; q < KEEP; ++q) {
      mv[xrL * 49 + li * KEEP + q] = tv[fn][q];
      mi[xrL * 49 + li * KEEP + q] = ti[fn][q];
    }
  }
  __syncthreads();
  if (t < 256) {
    float bvv[KEEP]; int bii[KEEP];
    #pragma unroll
    for (int q = 0; q < KEEP; ++q) { bvv[q] = -FLT_MAX; bii[q] = 0x7fffffff; }
    for (int c = 0; c < 4 * KEEP; ++c) {
      float cv = mv[t * 49 + c]; int ci = mi[t * 49 + c];
      if (cv > bvv[KEEP - 1] || (cv == bvv[KEEP - 1] && ci < bii[KEEP - 1])) {
        #pragma unroll
        for (int q = 0; q < KEEP; ++q) {
          if (cv > bvv[q] || (cv == bvv[q] && ci < bii[q])) {
            const float t0 = bvv[q]; bvv[q] = cv; cv = t0;
            const int   t1 = bii[q]; bii[q] = ci; ci = t1;
          }
        }
      }
    }
    const size_t base = ((size_t)(xbase + t) * NSPLIT + seg) * KEEP;
    #pragma unroll
    for (int q = 0; q < KEEP; ++q) { pval[base + q] = bvv[q]; pid[base + q] = bii[q]; }
  }
}

// ---------------------------------------------------------------------------
// Kernel 2: per row: merge 96 approx candidates -> top-28, exact f32 rescore,
// final top-8 (ties: lower id), gather + average. (unchanged from r9, passed)
// ---------------------------------------------------------------------------
__global__ __launch_bounds__(256)
void rescore_kernel(const float* __restrict__ X, const float* __restrict__ CB,
                    const float* __restrict__ c2g,
                    const float* __restrict__ pval, const int* __restrict__ pid,
                    float* __restrict__ out, float* __restrict__ out_ids) {
  const int row = blockIdx.x;
  const int t = threadIdx.x;
  __shared__ float xs[D_DIM];
  __shared__ int   scid[NC_RES];
  __shared__ float sv[NC_RES];
  __shared__ int   topid[KSEL];

  *(float4*)&xs[t * 4] = *(const float4*)(X + (size_t)row * D_DIM + t * 4);

  const int ncand = NSPLIT * KEEP;   // 96

  if (t < 64) {   // wave 0: lane holds cand t and (t<32 ? t+64 : none)
    float v0 = pval[(size_t)row * ncand + t];
    int   i0 = pid [(size_t)row * ncand + t];
    float v1 = -FLT_MAX; int i1 = 0x7fffffff;
    if (t < 32) {
      v1 = pval[(size_t)row * ncand + t + 64];
      i1 = pid [(size_t)row * ncand + t + 64];
    }
    for (int it = 0; it < NC_RES; ++it) {
      float bv; int bid;
      if (v0 > v1 || (v0 == v1 && i0 < i1)) { bv = v0; bid = i0; }
      else                                  { bv = v1; bid = i1; }
      #pragma unroll
      for (int off = 32; off >= 1; off >>= 1) {
        float ov = __shfl_xor(bv, off, 64);
        int   oi = __shfl_xor(bid, off, 64);
        if (ov > bv || (ov == bv && oi < bid)) { bv = ov; bid = oi; }
      }
      if (t == 0) scid[it] = bid;
      if (i0 == bid) v0 = -FLT_MAX;
      if (i1 == bid) v1 = -FLT_MAX;
    }
  }
  __syncthreads();

  const int w = t >> 6, ln = t & 63;
  for (int c = w; c < NC_RES; c += 4) {
    const int id = scid[c];
    const float* cr = CB + (size_t)id * D_DIM;
    float s = 0.f;
    #pragma unroll
    for (int i = 0; i < 4; ++i) {
      const float4 cv = *(const float4*)(cr + ln * 4 + i * 256);
      const float4 xv = *(const float4*)&xs[ln * 4 + i * 256];
      s += cv.x * xv.x + cv.y * xv.y + cv.z * xv.z + cv.w * xv.w;
    }
    #pragma unroll
    for (int off = 32; off >= 1; off >>= 1) s += __shfl_xor(s, off, 64);
    if (ln == 0) sv[c] = 2.f * s - c2g[id];
  }
  __syncthreads();

  if (t == 0) {
    float bv[KSEL]; int bi[KSEL];
    #pragma unroll
    for (int q = 0; q < KSEL; ++q) { bv[q] = -FLT_MAX; bi[q] = 0x7fffffff; }
    for (int c = 0; c < NC_RES; ++c) {
      float cv = sv[c]; int ci = scid[c];
      #pragma unroll
      for (int q = 0; q < KSEL; ++q) {
        if (cv > bv[q] || (cv == bv[q] && ci < bi[q])) {
          const float t0 = bv[q]; bv[q] = cv; cv = t0;
          const int   t1 = bi[q]; bi[q] = ci; ci = t1;
        }
      }
    }
    #pragma unroll
    for (int q = 0; q < KSEL; ++q) {
      topid[q] = bi[q];
      out_ids[(size_t)row * KSEL + q] = (float)bi[q];
    }
  }
  __syncthreads();

  float4 a = {0.f, 0.f, 0.f, 0.f};
  #pragma unroll
  for (int q = 0; q < KSEL; ++q) {
    const float4 cv = *(const float4*)(CB + (size_t)topid[q] * D_DIM + t * 4);
    a.x += cv.x; a.y += cv.y; a.z += cv.z; a.w += cv.w;
  }
  a.x *= 0.125f; a.y *= 0.125f; a.z *= 0.125f; a.w *= 0.125f;
  *(float4*)(out + (size_t)row * D_DIM + t * 4) = a;
}

// ---------------------------------------------------------------------------
extern "C" void kernel_launch(void* const* d_in, const int* in_sizes, int n_in,
                              void* d_out, int out_size, void* d_ws, size_t ws_size,
                              hipStream_t stream) {
  const float* X  = (const float*)d_in[0];
  const float* CB = (const float*)d_in[1];
  // d_in[2] = kcodes, fixed at 8 (compiled in)

  float* out     = (float*)d_out;
  float* out_ids = out + XN;

  const size_t XqB  = XN;                        // 8 MB (i8)
  const size_t CBqB = (size_t)C_TOTAL * D_DIM;   // 16 MB (i8)
  const size_t sxB  = R_TOTAL * 4;               // 32 KB
  const size_t scB  = C_TOTAL * 4;               // 64 KB
  const size_t c2B  = C_TOTAL * 4;               // 64 KB
  const size_t pvB  = (size_t)R_TOTAL * NSPLIT * KEEP * 4;  // 3 MB

  char* p = (char*)d_ws;
  signed char* CBq;
  if (ws_size >= XqB + CBqB + sxB + scB + c2B + 2 * pvB) {
    CBq = (signed char*)p; p += CBqB;
  } else {
    // CBq lives in d_out's outputs region (16MB of 32MB; overwritten at end)
    CBq = (signed char*)d_out;
  }
  signed char* Xq = (signed char*)p; p += XqB;
  float* sxg  = (float*)p; p += sxB;
  float* scg  = (float*)p; p += scB;
  float* c2g  = (float*)p; p += c2B;
  float* pval = (float*)p; p += pvB;
  int*   pid  = (int*)p;

  hipLaunchKernelGGL(quant_kernel, dim3((R_TOTAL + C_TOTAL) / 4), dim3(256), 0, stream,
                     X, CB, Xq, CBq, sxg, scg, c2g);
  hipLaunchKernelGGL(gemm_topk_kernel, dim3(32 * NSPLIT), dim3(512), 147456, stream,
                     Xq, CBq, c2g, scg, sxg, pval, pid);
  hipLaunchKernelGGL(rescore_kernel, dim3(R_TOTAL), dim3(256), 0, stream,
                     X, CB, c2g, pval, pid, out, out_ids);
}

// Round 11
// 541.062 us; speedup vs baseline: 1.2572x; 1.2418x over previous
//
#include <hip/hip_runtime.h>
#include <hip/hip_bf16.h>
#include <float.h>

// Problem constants: B=4, S=2048, D=1024, C=16384, k=8
#define R_TOTAL 8192
#define D_DIM   1024
#define C_TOTAL 16384
#define KSEL    8
#define XN  ((size_t)R_TOTAL * D_DIM)   // 8,388,608
#define CBN ((size_t)C_TOTAL * D_DIM)   // 16,777,216
#define NSPLIT  8
#define SEGC    (C_TOTAL / NSPLIT)      // 2048 codes per segment (per block)
#define NCHUNK  (SEGC / 256)            // 8 chunks of 256 codes
#define NKT     (NCHUNK * 16)           // 128 K-tiles (BK=64) per block
#define NC_RES  16                      // candidates exact-rescored per row

typedef __attribute__((ext_vector_type(8)))  short short8v;   // 8 bf16
typedef __attribute__((ext_vector_type(16))) float f32x16;

__device__ __forceinline__ unsigned short f2bf(float f) {  // RNE f32->bf16
  unsigned u = __float_as_uint(f);
  u = (u + 0x7fffu + ((u >> 16) & 1u)) >> 16;
  return (unsigned short)u;
}

__device__ __forceinline__ void gload_lds16(const void* g, void* l) {
  __builtin_amdgcn_global_load_lds((const __attribute__((address_space(1))) void*)g,
                                   (__attribute__((address_space(3))) void*)l, 16, 0, 0);
}

// ---------------------------------------------------------------------------
// Kernel 0: fused f32->bf16 conversion (X and CB) + c2 for CB rows.
// One wave per row (reads each CB row once instead of twice).
// ---------------------------------------------------------------------------
__global__ __launch_bounds__(256)
void cvt_c2_kernel(const float* __restrict__ X, const float* __restrict__ CB,
                   unsigned short* __restrict__ Xb, unsigned short* __restrict__ CBb,
                   float* __restrict__ c2g) {
  const int row  = blockIdx.x * 4 + (threadIdx.x >> 6);
  const int lane = threadIdx.x & 63;
  const bool isCB = row >= R_TOTAL;
  const int rl = isCB ? row - R_TOTAL : row;
  const float* src = (isCB ? CB : X) + (size_t)rl * D_DIM;
  unsigned short* dst = (isCB ? CBb : Xb) + (size_t)rl * D_DIM;

  float ss = 0.f;
  #pragma unroll
  for (int i = 0; i < 4; ++i) {
    const float4 v = *(const float4*)(src + i * 256 + lane * 4);
    if (isCB) ss += v.x * v.x + v.y * v.y + v.z * v.z + v.w * v.w;
    ushort4 o;
    o.x = f2bf(v.x); o.y = f2bf(v.y); o.z = f2bf(v.z); o.w = f2bf(v.w);
    *(ushort4*)(dst + i * 256 + lane * 4) = o;
  }
  if (isCB) {
    #pragma unroll
    for (int off = 32; off >= 1; off >>= 1) ss += __shfl_xor(ss, off, 64);
    if (lane == 0) c2g[rl] = ss;
  }
}

// ---------------------------------------------------------------------------
// Kernel 1: bf16 MFMA GEMM (S^T: 256 codes x 256 xrows tile) with fused
// per-xrow approximate top-8 per 2048-code segment.
// VERBATIM round-6 kernel (best measured: 418us): E/O one-phase-ahead
// fragment pipeline, 4 barriers/tile, vmcnt(0)@p3.
// 512 thr = 8 waves (2 code-halves x 4 xrow-quarters); per wave 128x64 out
// via mfma_f32_32x32x16_bf16: acc[fm=4][fn=2] f32x16.
// LDS 136KB: A dbuf 2x32KB | X dbuf 2x32KB | c2 seg 8KB.
// Swizzle: rows [*][64] bf16 (128B), kbyte ^= ((row&7)<<4), applied on the
// global source (linear gload_lds dest) + on ds_read addrs (both-sides, #21).
// ---------------------------------------------------------------------------
__global__ __launch_bounds__(512, 2)
void gemm_topk_kernel(const unsigned short* __restrict__ Xb,
                      const unsigned short* __restrict__ CBb,
                      const float* __restrict__ c2g,
                      float* __restrict__ pval, int* __restrict__ pid) {
  extern __shared__ char smem[];
  float* c2s = (float*)(smem + 131072);

  const int t   = threadIdx.x;
  const int wid = t >> 6, l = t & 63;
  const int wr  = wid >> 2;          // 0..1: code half (128 rows)
  const int wc  = wid & 3;           // 0..3: xrow quarter (64 cols)
  const int l31 = l & 31, hi = l >> 5;

  const int xt    = blockIdx.x & 31;        // 32 xrow tiles
  const int seg   = blockIdx.x >> 5;        // 8 segments
  const int xbase = xt * 256;
  const int cb0   = seg * SEGC;

  // preload segment c2 into LDS (512 thr x float4 = 2048 f32)
  *(float4*)&c2s[t * 4] = *(const float4*)(c2g + cb0 + t * 4);

  // staging: issue i covers rows i*64+(t>>3); 16B col chunk (t&7), swizzled src
  const int srow = t >> 3;
  const int sswz = (((t & 7) * 16) ^ ((srow & 7) << 4)) >> 1;  // elem offset
  const int fswz = (l & 7) << 4;                                // read swizzle

  f32x16 acc[4][2];
  float tv[2][KSEL]; int ti[2][KSEL];
  #pragma unroll
  for (int fm = 0; fm < 4; ++fm)
    #pragma unroll
    for (int fn = 0; fn < 2; ++fn)
      #pragma unroll
      for (int r = 0; r < 16; ++r) acc[fm][fn][r] = 0.f;
  #pragma unroll
  for (int fn = 0; fn < 2; ++fn)
    #pragma unroll
    for (int q = 0; q < KSEL; ++q) { tv[fn][q] = -FLT_MAX; ti[fn][q] = 0; }

  auto STAGE_A = [&](int g) {   // 4 loads: codes half-tiles of K-tile g
    const int kbase = (g & 15) * 64;
    const int arow0 = cb0 + (g >> 4) * 256;
    char* As = smem + (g & 1) * 32768;
    #pragma unroll
    for (int i = 0; i < 4; ++i)
      gload_lds16(CBb + (size_t)(arow0 + i * 64 + srow) * D_DIM + kbase + sswz,
                  As + (i * 512 + t) * 16);
  };
  auto STAGE_X = [&](int g) {   // 4 loads: xrow half-tiles of K-tile g
    const int kbase = (g & 15) * 64;
    char* Xs = smem + 65536 + (g & 1) * 32768;
    #pragma unroll
    for (int i = 0; i < 4; ++i)
      gload_lds16(Xb + (size_t)(xbase + i * 64 + srow) * D_DIM + kbase + sswz,
                  Xs + (i * 512 + t) * 16);
  };

  // two named fragment sets (static indexing only - rule 20)
  short8v avE[4], bvE[2], avO[4], bvO[2];

#define READ_FRAGS(AV, BV, ABUF, XBUF, P)                                       \
  {                                                                             \
    const int kb_ = ((P) * 32 + hi * 16) ^ fswz;                                \
    _Pragma("unroll")                                                           \
    for (int fm_ = 0; fm_ < 4; ++fm_)                                           \
      AV[fm_] = *(const short8v*)((ABUF) +                                      \
                    (wr * 128 + fm_ * 32 + l31) * 128 + kb_);                   \
    _Pragma("unroll")                                                           \
    for (int fn_ = 0; fn_ < 2; ++fn_)                                           \
      BV[fn_] = *(const short8v*)((XBUF) +                                      \
                    (wc * 64 + fn_ * 32 + l31) * 128 + kb_);                    \
  }

#define MFMA8(AV, BV)                                                           \
  {                                                                             \
    __builtin_amdgcn_s_setprio(1);                                              \
    _Pragma("unroll")                                                           \
    for (int fm_ = 0; fm_ < 4; ++fm_)                                           \
      _Pragma("unroll")                                                         \
      for (int fn_ = 0; fn_ < 2; ++fn_)                                         \
        acc[fm_][fn_] = __builtin_amdgcn_mfma_f32_32x32x16_bf16(                \
            AV[fm_], BV[fn_], acc[fm_][fn_], 0, 0, 0);                          \
    __builtin_amdgcn_s_setprio(0);                                              \
    __builtin_amdgcn_sched_barrier(0);                                          \
  }

  // ---- prologue: stage tile 0, drain, pre-read ks0 frags ----
  STAGE_A(0); STAGE_X(0);
  asm volatile("s_waitcnt vmcnt(0) lgkmcnt(0)" ::: "memory");
  __builtin_amdgcn_s_barrier();
  __builtin_amdgcn_sched_barrier(0);
  READ_FRAGS(avE, bvE, (const char*)smem, (const char*)smem + 65536, 0);

  for (int g = 0; g < NKT; ++g) {
    const char* As  = smem + (g & 1) * 32768;
    const char* Xs  = smem + 65536 + (g & 1) * 32768;
    const char* Asn = smem + ((g + 1) & 1) * 32768;
    const char* Xsn = smem + 65536 + ((g + 1) & 1) * 32768;
    const bool more = (g + 1 < NKT);

    // --- p0: consume E(ks0), issue O(ks1), stage A(g+1) ---
    READ_FRAGS(avO, bvO, As, Xs, 1);
    if (more) STAGE_A(g + 1);
    __builtin_amdgcn_s_barrier();
    MFMA8(avE, bvE);

    // --- p1: consume O(ks1), issue E(ks2), stage X(g+1) ---
    READ_FRAGS(avE, bvE, As, Xs, 2);
    if (more) STAGE_X(g + 1);
    __builtin_amdgcn_s_barrier();
    MFMA8(avO, bvO);

    // --- p2: consume E(ks2), issue O(ks3) ---
    READ_FRAGS(avO, bvO, As, Xs, 3);
    __builtin_amdgcn_s_barrier();
    MFMA8(avE, bvE);

    // --- p3: consume O(ks3), pre-read E(ks0 of g+1) from other buffer ---
    asm volatile("s_waitcnt vmcnt(0)" ::: "memory");  // stage g+1: 2-3 phases old
    __builtin_amdgcn_s_barrier();                      // ALL waves' stages landed
    __builtin_amdgcn_sched_barrier(0);
    if (more) READ_FRAGS(avE, bvE, Asn, Xsn, 0);
    MFMA8(avO, bvO);

    if ((g & 15) == 15) {
      // -------- selection epilogue for chunk ch (registers + c2s only) -----
      const int ch = g >> 4;
      #pragma unroll
      for (int fm = 0; fm < 4; ++fm) {
        const int rloc = ch * 256 + wr * 128 + fm * 32 + hi * 4;
        const int idb  = cb0 + ch * 256 + wr * 128 + fm * 32 + hi * 4;
        #pragma unroll
        for (int q = 0; q < 4; ++q) {
          const float4 cq = *(const float4*)&c2s[rloc + q * 8];
          #pragma unroll
          for (int fn = 0; fn < 2; ++fn) {
            #pragma unroll
            for (int r = 0; r < 4; ++r) {
              const float c2v = (r == 0) ? cq.x : (r == 1) ? cq.y : (r == 2) ? cq.z : cq.w;
              const float s = 2.f * acc[fm][fn][q * 4 + r] - c2v;
              if (s > tv[fn][KSEL - 1]) {      // strict >: ids scanned ascending
                float cv = s; int ci = idb + q * 8 + r;
                #pragma unroll
                for (int q2 = 0; q2 < KSEL; ++q2) {
                  if (cv > tv[fn][q2]) {
                    const float t0 = tv[fn][q2]; tv[fn][q2] = cv; cv = t0;
                    const int   t1 = ti[fn][q2]; ti[fn][q2] = ci; ci = t1;
                  }
                }
              }
            }
          }
        }
      }
      #pragma unroll
      for (int fm = 0; fm < 4; ++fm)
        #pragma unroll
        for (int fn = 0; fn < 2; ++fn)
          #pragma unroll
          for (int r = 0; r < 16; ++r) acc[fm][fn][r] = 0.f;
    }
  }

#undef READ_FRAGS
#undef MFMA8

  // -------- merge 4 lane-lists per xrow, write per-segment top-8 --------
  asm volatile("s_waitcnt vmcnt(0) lgkmcnt(0)" ::: "memory");
  __builtin_amdgcn_s_barrier();
  float* mv = (float*)smem;            // [256 xrows][4 lists][8] = 32KB
  int*   mi = (int*)(smem + 32768);
  #pragma unroll
  for (int fn = 0; fn < 2; ++fn) {
    const int xrL = wc * 64 + fn * 32 + l31;
    const int li  = wr * 2 + hi;
    #pragma unroll
    for (int q = 0; q < KSEL; ++q) {
      mv[xrL * 32 + li * 8 + q] = tv[fn][q];
      mi[xrL * 32 + li * 8 + q] = ti[fn][q];
    }
  }
  __syncthreads();
  if (t < 256) {
    float bvv[KSEL]; int bii[KSEL];
    #pragma unroll
    for (int q = 0; q < KSEL; ++q) { bvv[q] = -FLT_MAX; bii[q] = 0x7fffffff; }
    for (int c = 0; c < 32; ++c) {
      float cv = mv[t * 32 + c]; int ci = mi[t * 32 + c];
      if (cv > bvv[KSEL - 1] || (cv == bvv[KSEL - 1] && ci < bii[KSEL - 1])) {
        #pragma unroll
        for (int q = 0; q < KSEL; ++q) {
          if (cv > bvv[q] || (cv == bvv[q] && ci < bii[q])) {
            const float t0 = bvv[q]; bvv[q] = cv; cv = t0;
            const int   t1 = bii[q]; bii[q] = ci; ci = t1;
          }
        }
      }
    }
    const size_t base = ((size_t)(xbase + t) * NSPLIT + seg) * KSEL;
    #pragma unroll
    for (int q = 0; q < KSEL; ++q) { pval[base + q] = bvv[q]; pid[base + q] = bii[q]; }
  }
}

// ---------------------------------------------------------------------------
// Kernel 2: per row: merge 64 approx candidates -> top-16, exact f32 rescore
// of those 16, final top-8 (ties: lower id), gather + average.
// (r6 rescore with NC_RES 24->16: gather traffic 786MB -> 524MB.
//  Margin: bf16 score noise sigma~0.1; rank-8..16 order-stat gap ~8-10 sigma.)
// ---------------------------------------------------------------------------
__global__ __launch_bounds__(256)
void rescore_kernel(const float* __restrict__ X, const float* __restrict__ CB,
                    const float* __restrict__ c2g,
                    const float* __restrict__ pval, const int* __restrict__ pid,
                    float* __restrict__ out, float* __restrict__ out_ids) {
  const int row = blockIdx.x;
  const int t = threadIdx.x;
  __shared__ float xs[D_DIM];
  __shared__ int   scid[NC_RES];
  __shared__ float sv[NC_RES];
  __shared__ int   topid[KSEL];

  *(float4*)&xs[t * 4] = *(const float4*)(X + (size_t)row * D_DIM + t * 4);

  const int ncand = NSPLIT * KSEL;          // 64

  if (t < 64) {   // wave 0: merge candidates by approx score -> top-NC ids
    float v   = pval[(size_t)row * ncand + t];
    int   idv = pid [(size_t)row * ncand + t];
    for (int it = 0; it < NC_RES; ++it) {
      float bv = v; int bid = idv;
      #pragma unroll
      for (int off = 32; off >= 1; off >>= 1) {
        float ov = __shfl_xor(bv, off, 64);
        int   oi = __shfl_xor(bid, off, 64);
        if (ov > bv || (ov == bv && oi < bid)) { bv = ov; bid = oi; }
      }
      if (t == 0) scid[it] = bid;
      if (idv == bid) v = -FLT_MAX;   // remove winner (ids unique)
    }
  }
  __syncthreads();

  const int w = t >> 6, ln = t & 63;
  for (int c = w; c < NC_RES; c += 4) {
    const int id = scid[c];
    const float* cr = CB + (size_t)id * D_DIM;
    float s = 0.f;
    #pragma unroll
    for (int i = 0; i < 4; ++i) {
      const float4 cv = *(const float4*)(cr + ln * 4 + i * 256);
      const float4 xv = *(const float4*)&xs[ln * 4 + i * 256];
      s += cv.x * xv.x + cv.y * xv.y + cv.z * xv.z + cv.w * xv.w;
    }
    #pragma unroll
    for (int off = 32; off >= 1; off >>= 1) s += __shfl_xor(s, off, 64);
    if (ln == 0) sv[c] = 2.f * s - c2g[id];
  }
  __syncthreads();

  if (t == 0) {
    float bv[KSEL]; int bi[KSEL];
    #pragma unroll
    for (int q = 0; q < KSEL; ++q) { bv[q] = -FLT_MAX; bi[q] = 0x7fffffff; }
    for (int c = 0; c < NC_RES; ++c) {
      float cv = sv[c]; int ci = scid[c];
      #pragma unroll
      for (int q = 0; q < KSEL; ++q) {
        if (cv > bv[q] || (cv == bv[q] && ci < bi[q])) {
          const float t0 = bv[q]; bv[q] = cv; cv = t0;
          const int   t1 = bi[q]; bi[q] = ci; ci = t1;
        }
      }
    }
    #pragma unroll
    for (int q = 0; q < KSEL; ++q) {
      topid[q] = bi[q];
      out_ids[(size_t)row * KSEL + q] = (float)bi[q];
    }
  }
  __syncthreads();

  float4 a = {0.f, 0.f, 0.f, 0.f};
  #pragma unroll
  for (int q = 0; q < KSEL; ++q) {
    const float4 cv = *(const float4*)(CB + (size_t)topid[q] * D_DIM + t * 4);
    a.x += cv.x; a.y += cv.y; a.z += cv.z; a.w += cv.w;
  }
  a.x *= 0.125f; a.y *= 0.125f; a.z *= 0.125f; a.w *= 0.125f;
  *(float4*)(out + (size_t)row * D_DIM + t * 4) = a;
}

// ---------------------------------------------------------------------------
extern "C" void kernel_launch(void* const* d_in, const int* in_sizes, int n_in,
                              void* d_out, int out_size, void* d_ws, size_t ws_size,
                              hipStream_t stream) {
  const float* X  = (const float*)d_in[0];
  const float* CB = (const float*)d_in[1];
  // d_in[2] = kcodes, fixed at 8 (compiled in)

  float* out     = (float*)d_out;
  float* out_ids = out + XN;

  const size_t XbB  = XN * 2;        // 16 MB
  const size_t CBbB = CBN * 2;       // 32 MB
  const size_t c2B  = C_TOTAL * 4;   // 64 KB
  const size_t pvB  = (size_t)R_TOTAL * NSPLIT * KSEL * 4;  // 2 MB

  char* p = (char*)d_ws;
  unsigned short* Xb;
  unsigned short* CBb;
  if (ws_size >= XbB + CBbB + c2B + 2 * pvB) {
    Xb  = (unsigned short*)p; p += XbB;
    CBb = (unsigned short*)p; p += CBbB;
  } else {
    // CB bf16 lives in d_out's outputs region (overwritten at the very end)
    CBb = (unsigned short*)d_out;
    Xb  = (unsigned short*)p; p += XbB;
  }
  float* c2   = (float*)p; p += c2B;
  float* pval = (float*)p; p += pvB;
  int*   pid  = (int*)p;

  hipLaunchKernelGGL(cvt_c2_kernel, dim3((R_TOTAL + C_TOTAL) / 4), dim3(256), 0, stream,
                     X, CB, Xb, CBb, c2);
  hipLaunchKernelGGL(gemm_topk_kernel, dim3(32 * NSPLIT), dim3(512), 136 * 1024, stream,
                     Xb, CBb, c2, pval, pid);
  hipLaunchKernelGGL(rescore_kernel, dim3(R_TOTAL), dim3(256), 0, stream,
                     X, CB, c2, pval, pid, out, out_ids);
}